// Round 7
// baseline (826.279 us; speedup 1.0000x reference)
//
#include <hip/hip_runtime.h>

#define NNODES 40000
#define NEDGES 640000
#define NFEAT  256
#define NHID   128

// ---- range partition geometry ----
#define RSHIFT 7                        // 128 nodes per range
#define RNODES 128
#define NR     313                      // ceil(40000/128)
#define CAPR   3000                     // slots per range; E[count]=2048, 21 sigma margin
#define PARTB  250                      // partition blocks
#define EPB    2560                     // edges per partition block (10/thread)
#define GEMM_BLOCKS (NNODES / 64)       // 625

// ---- workspace layout (bytes) ----
#define SUP_OFF  0u                     // support bf16: 40000*128*2 = 10,240,000
#define WT_OFF   10240000u              // Wt bf16: 128*256*2 = 65,536
#define RC_OFF   10305536u              // range_cursor: 313 u32 (padded)
#define EBIN_OFF 10307584u              // ebin: 313*3000*8 = 7,512,000 -> ends 17,819,584
#define WS_NEEDED 18145536u             // unchanged gate (fits)

typedef float floatx4 __attribute__((ext_vector_type(4)));
typedef __bf16 bf16x8 __attribute__((ext_vector_type(8)));
typedef unsigned short ushort8 __attribute__((ext_vector_type(8)));
union BfFrag { ushort8 s; bf16x8 b; };

__device__ __forceinline__ unsigned short f2bf(float f) {
    unsigned int u = __float_as_uint(f);
    u = (u + 0x7FFFu + ((u >> 16) & 1u)) >> 16;   // RNE
    return (unsigned short)u;
}

// decode 2x(2 bf16) -> float4
__device__ __forceinline__ float4 bf4(unsigned int lo, unsigned int hi) {
    float4 v;
    v.x = __uint_as_float(lo << 16);
    v.y = __uint_as_float(lo & 0xFFFF0000u);
    v.z = __uint_as_float(hi << 16);
    v.w = __uint_as_float(hi & 0xFFFF0000u);
    return v;
}

// ---------------------------------------------------------------------------
// K0: setup — zero range_cursor AND Wt[h][k] = bf16(W[k][h]).
// ---------------------------------------------------------------------------
__global__ __launch_bounds__(256) void setup_wt_cur(const float* __restrict__ W,
                                                    unsigned short* __restrict__ Wt,
                                                    unsigned int* __restrict__ range_cursor) {
    const int i = blockIdx.x * 256 + threadIdx.x;
    if (i < NR) range_cursor[i] = 0;
    if (i < NFEAT * NHID) {
        const int h = i >> 8;
        const int k = i & 255;
        Wt[i] = f2bf(W[k * NHID + h]);
    }
}

// ---------------------------------------------------------------------------
// K1: GEMM (blocks [0,625)) || edge partition (blocks [625,875)).
// Partition: LDS histogram over 313 dst-ranges -> ~300 global atomics/block
// -> LDS-grouped staging -> CONTIGUOUS-run writes of 8B records into
// per-range bins. (R6: this removed gemm_fill from the top-5 — the 640k
// random 4B stores / line writebacks were indeed the R0-R4 fill wall.)
// ---------------------------------------------------------------------------
__global__ __launch_bounds__(256) void gemm_fill(const float* __restrict__ x,
                                                 const unsigned short* __restrict__ Wt,
                                                 unsigned short* __restrict__ support,
                                                 const int* __restrict__ ei,
                                                 const float* __restrict__ ew,
                                                 unsigned int* __restrict__ range_cursor,
                                                 unsigned long long* __restrict__ ebin) {
    const int tid = threadIdx.x;

    if (blockIdx.x >= GEMM_BLOCKS) {
        // ---- partition path ----
        __shared__ unsigned int hist[320];
        __shared__ unsigned int sA[320], sB[320];
        __shared__ unsigned int lstart[320];
        __shared__ unsigned int gbase[320];
        __shared__ unsigned int ldscur[320];
        __shared__ unsigned long long recbuf[EPB];
        __shared__ unsigned short rbuf[EPB];

        const int pb   = blockIdx.x - GEMM_BLOCKS;
        const int base = pb * EPB + tid;

        for (int i = tid; i < 320; i += 256) { hist[i] = 0; ldscur[i] = 0; }
        __syncthreads();

        // pass 1: histogram dst ranges
        int dst[10];
        #pragma unroll
        for (int j = 0; j < 10; j++) dst[j] = ei[NEDGES + base + j * 256];
        #pragma unroll
        for (int j = 0; j < 10; j++) atomicAdd(&hist[dst[j] >> RSHIFT], 1u);
        __syncthreads();

        // exclusive scan of hist (Hillis-Steele over 320, 9 passes)
        for (int i = tid; i < 320; i += 256) sA[i] = (i > 0) ? hist[i - 1] : 0u;
        __syncthreads();
        unsigned int* cur = sA;
        unsigned int* nxt = sB;
        for (int off = 1; off < 320; off <<= 1) {
            for (int i = tid; i < 320; i += 256)
                nxt[i] = cur[i] + ((i >= off) ? cur[i - off] : 0u);
            __syncthreads();
            unsigned int* t = cur; cur = nxt; nxt = t;
        }
        for (int i = tid; i < 320; i += 256) {
            lstart[i] = cur[i];
            gbase[i]  = (i < NR && hist[i] > 0u)
                        ? atomicAdd(&range_cursor[i], hist[i]) : 0u;
        }
        __syncthreads();

        // pass 2: stage records grouped by range
        int src[10];
        float w[10];
        #pragma unroll
        for (int j = 0; j < 10; j++) {
            src[j] = ei[base + j * 256];
            w[j]   = ew[base + j * 256];
        }
        #pragma unroll
        for (int j = 0; j < 10; j++) {
            const int r  = dst[j] >> RSHIFT;
            const unsigned int lr = atomicAdd(&ldscur[r], 1u);
            const unsigned int pos = lstart[r] + lr;
            recbuf[pos] = ((unsigned long long)f2bf(w[j]) << 32)
                        | ((unsigned long long)(dst[j] & (RNODES - 1)) << 16)
                        | (unsigned long long)(unsigned int)src[j];
            rbuf[pos] = (unsigned short)r;
        }
        __syncthreads();

        // writeout: consecutive staging entries of a range -> consecutive slots
        for (int i = tid; i < EPB; i += 256) {
            const int r = rbuf[i];
            const unsigned int slot = gbase[r] + ((unsigned int)i - lstart[r]);
            if (slot < CAPR)
                ebin[(size_t)r * CAPR + slot] = recbuf[i];
        }
        return;
    }

    // ---- GEMM path (unchanged) ----
    const int lane = tid & 63;
    const int wv   = tid >> 6;
    const int m    = lane & 15;
    const int quad = lane >> 4;
    const int node = blockIdx.x * 64 + wv * 16 + m;

    BfFrag afrag[8];
    const float* xrow = x + (size_t)node * NFEAT + quad * 8;
    #pragma unroll
    for (int ks = 0; ks < 8; ks++) {
        float4 f0 = *(const float4*)(xrow + ks * 32);
        float4 f1 = *(const float4*)(xrow + ks * 32 + 4);
        afrag[ks].s[0] = f2bf(f0.x); afrag[ks].s[1] = f2bf(f0.y);
        afrag[ks].s[2] = f2bf(f0.z); afrag[ks].s[3] = f2bf(f0.w);
        afrag[ks].s[4] = f2bf(f1.x); afrag[ks].s[5] = f2bf(f1.y);
        afrag[ks].s[6] = f2bf(f1.z); afrag[ks].s[7] = f2bf(f1.w);
    }

    floatx4 acc[8];
    #pragma unroll
    for (int nt = 0; nt < 8; nt++) acc[nt] = (floatx4){0.f, 0.f, 0.f, 0.f};

    #pragma unroll
    for (int nt = 0; nt < 8; nt++) {
        const unsigned short* wrow = Wt + (size_t)(nt * 16 + m) * NFEAT + quad * 8;
        #pragma unroll
        for (int ks = 0; ks < 8; ks++) {
            BfFrag bfrag;
            bfrag.s = *(const ushort8*)(wrow + ks * 32);
            acc[nt] = __builtin_amdgcn_mfma_f32_16x16x32_bf16(afrag[ks].b, bfrag.b,
                                                              acc[nt], 0, 0, 0);
        }
    }

    const int row0 = blockIdx.x * 64 + wv * 16 + quad * 4;
    #pragma unroll
    for (int nt = 0; nt < 8; nt++) {
        #pragma unroll
        for (int r = 0; r < 4; r++) {
            support[(size_t)(row0 + r) * NHID + nt * 16 + m] = f2bf(acc[nt][r]);
        }
    }
}

// ---------------------------------------------------------------------------
// K2: gather — one block of 512 thr (8 waves) per dst-range.
// acc[128][128] f32 in LDS (64KB). R6's version was a serial 1-record chain
// (696us, 9% occ); this one restores gather_csr's MLP: each wave's four
// 16-lane quarters run independent record streams, 4-deep ILP => 16 records
// in flight per wave, 128 per block. Per record: coalesced 8B bin read
// (4 quarters = 32B contiguous), 16-lane x 16B support-row read, 8
// fire-and-forget ds_add_f32 per lane. Epilogue: bias+relu, coalesced.
// ---------------------------------------------------------------------------
__global__ __launch_bounds__(512) void gather_range(
        const unsigned int* __restrict__ range_cursor,
        const unsigned long long* __restrict__ ebin,
        const unsigned short* __restrict__ support,
        const float* __restrict__ b,
        float* __restrict__ out) {
    __shared__ float accf[RNODES * NHID];   // 64 KB

    const int r    = blockIdx.x;
    const int tid  = threadIdx.x;
    const int lane = tid & 63;
    const int wv   = tid >> 6;     // 8 waves
    const int q    = lane >> 4;    // quarter = record-stream selector
    const int ql   = lane & 15;    // lane-in-quarter: hids [8*ql, 8*ql+7]

    float4* acc4 = (float4*)accf;
    #pragma unroll
    for (int i = 0; i < (RNODES * NHID / 4) / 512; i++)
        acc4[tid + i * 512] = make_float4(0.f, 0.f, 0.f, 0.f);
    __syncthreads();

    unsigned int cnt = range_cursor[r];
    if (cnt > CAPR) cnt = CAPR;
    const unsigned long long* bin  = ebin + (size_t)r * CAPR;
    const uint4*              sup4 = (const uint4*)support;  // 8 bf16/uint4, row stride 16

    // wave wv owns records [kb, ke)
    const unsigned int kb = (cnt * (unsigned int)wv) >> 3;
    const unsigned int ke = (cnt * (unsigned int)(wv + 1)) >> 3;

    unsigned int i = kb;
    for (; i + 16 <= ke; i += 16) {
        const unsigned long long r0 = bin[i + 0  + q];
        const unsigned long long r1 = bin[i + 4  + q];
        const unsigned long long r2 = bin[i + 8  + q];
        const unsigned long long r3 = bin[i + 12 + q];
        const uint4 u0 = sup4[(size_t)(r0 & 0xFFFFu) * 16 + ql];
        const uint4 u1 = sup4[(size_t)(r1 & 0xFFFFu) * 16 + ql];
        const uint4 u2 = sup4[(size_t)(r2 & 0xFFFFu) * 16 + ql];
        const uint4 u3 = sup4[(size_t)(r3 & 0xFFFFu) * 16 + ql];
        const float w0 = __uint_as_float(((unsigned int)(r0 >> 32)) << 16);
        const float w1 = __uint_as_float(((unsigned int)(r1 >> 32)) << 16);
        const float w2 = __uint_as_float(((unsigned int)(r2 >> 32)) << 16);
        const float w3 = __uint_as_float(((unsigned int)(r3 >> 32)) << 16);
        const int   d0 = (int)((r0 >> 16) & (RNODES - 1));
        const int   d1 = (int)((r1 >> 16) & (RNODES - 1));
        const int   d2 = (int)((r2 >> 16) & (RNODES - 1));
        const int   d3 = (int)((r3 >> 16) & (RNODES - 1));

        {
            float* a = &accf[d0 * NHID + ql * 8];
            const float4 vl = bf4(u0.x, u0.y), vh = bf4(u0.z, u0.w);
            atomicAdd(a + 0, w0 * vl.x); atomicAdd(a + 1, w0 * vl.y);
            atomicAdd(a + 2, w0 * vl.z); atomicAdd(a + 3, w0 * vl.w);
            atomicAdd(a + 4, w0 * vh.x); atomicAdd(a + 5, w0 * vh.y);
            atomicAdd(a + 6, w0 * vh.z); atomicAdd(a + 7, w0 * vh.w);
        }
        {
            float* a = &accf[d1 * NHID + ql * 8];
            const float4 vl = bf4(u1.x, u1.y), vh = bf4(u1.z, u1.w);
            atomicAdd(a + 0, w1 * vl.x); atomicAdd(a + 1, w1 * vl.y);
            atomicAdd(a + 2, w1 * vl.z); atomicAdd(a + 3, w1 * vl.w);
            atomicAdd(a + 4, w1 * vh.x); atomicAdd(a + 5, w1 * vh.y);
            atomicAdd(a + 6, w1 * vh.z); atomicAdd(a + 7, w1 * vh.w);
        }
        {
            float* a = &accf[d2 * NHID + ql * 8];
            const float4 vl = bf4(u2.x, u2.y), vh = bf4(u2.z, u2.w);
            atomicAdd(a + 0, w2 * vl.x); atomicAdd(a + 1, w2 * vl.y);
            atomicAdd(a + 2, w2 * vl.z); atomicAdd(a + 3, w2 * vl.w);
            atomicAdd(a + 4, w2 * vh.x); atomicAdd(a + 5, w2 * vh.y);
            atomicAdd(a + 6, w2 * vh.z); atomicAdd(a + 7, w2 * vh.w);
        }
        {
            float* a = &accf[d3 * NHID + ql * 8];
            const float4 vl = bf4(u3.x, u3.y), vh = bf4(u3.z, u3.w);
            atomicAdd(a + 0, w3 * vl.x); atomicAdd(a + 1, w3 * vl.y);
            atomicAdd(a + 2, w3 * vl.z); atomicAdd(a + 3, w3 * vl.w);
            atomicAdd(a + 4, w3 * vh.x); atomicAdd(a + 5, w3 * vh.y);
            atomicAdd(a + 6, w3 * vh.z); atomicAdd(a + 7, w3 * vh.w);
        }
    }

    if (i < ke) {   // masked tail: up to 15 records, 4 streams keep ILP
        #pragma unroll
        for (int j = 0; j < 4; j++) {
            const unsigned int e = i + 4 * j + q;
            const bool valid = e < ke;
            const unsigned long long rec = bin[valid ? e : kb];
            const float w  = valid ? __uint_as_float(((unsigned int)(rec >> 32)) << 16) : 0.f;
            const int   dl = (int)((rec >> 16) & (RNODES - 1));
            const uint4 u  = sup4[(size_t)(rec & 0xFFFFu) * 16 + ql];
            const float4 vl = bf4(u.x, u.y), vh = bf4(u.z, u.w);
            float* a = &accf[dl * NHID + ql * 8];
            atomicAdd(a + 0, w * vl.x); atomicAdd(a + 1, w * vl.y);
            atomicAdd(a + 2, w * vl.z); atomicAdd(a + 3, w * vl.w);
            atomicAdd(a + 4, w * vh.x); atomicAdd(a + 5, w * vh.y);
            atomicAdd(a + 6, w * vh.z); atomicAdd(a + 7, w * vh.w);
        }
    }
    __syncthreads();

    const int node0 = r * RNODES;
    int nn = NNODES - node0;
    if (nn > RNODES) nn = RNODES;
    const float4* b4p = (const float4*)b;
    float4*       o4  = (float4*)out;
    for (int idx = tid; idx < nn * (NHID / 4); idx += 512) {
        const int row = idx >> 5;
        const int c4  = idx & 31;
        float4 v  = acc4[row * 32 + c4];
        float4 bb = b4p[c4];
        v.x = fmaxf(v.x + bb.x, 0.f);
        v.y = fmaxf(v.y + bb.y, 0.f);
        v.z = fmaxf(v.z + bb.z, 0.f);
        v.w = fmaxf(v.w + bb.w, 0.f);
        o4[(size_t)(node0 + row) * (NHID / 4) + c4] = v;
    }
}

// ---------------------------------------------------------------------------
// Fallback path (ws too small): fp32 GEMM + atomic scatter
// ---------------------------------------------------------------------------
__global__ __launch_bounds__(256) void gemm_xw(const float* __restrict__ x,
                                               const float* __restrict__ W,
                                               float* __restrict__ support) {
    __shared__ float xs[64 * NFEAT];
    const int tid   = threadIdx.x;
    const int node0 = blockIdx.x * 64;

    const float4* xg  = (const float4*)(x + (size_t)node0 * NFEAT);
    float4*       xs4 = (float4*)xs;
    #pragma unroll
    for (int i = tid; i < 64 * (NFEAT / 4); i += 256) xs4[i] = xg[i];
    __syncthreads();

    const int hg = tid & 31;
    const int ng = tid >> 5;
    const float4* W4 = (const float4*)W;

    float4 acc[8];
    #pragma unroll
    for (int n = 0; n < 8; n++) acc[n] = make_float4(0.f, 0.f, 0.f, 0.f);

    #pragma unroll 4
    for (int k = 0; k < NFEAT; k++) {
        float4 w = W4[k * (NHID / 4) + hg];
        #pragma unroll
        for (int n = 0; n < 8; n++) {
            float xv = xs[(ng * 8 + n) * NFEAT + k];
            acc[n].x = fmaf(xv, w.x, acc[n].x);
            acc[n].y = fmaf(xv, w.y, acc[n].y);
            acc[n].z = fmaf(xv, w.z, acc[n].z);
            acc[n].w = fmaf(xv, w.w, acc[n].w);
        }
    }

    float4* out4 = (float4*)support;
    #pragma unroll
    for (int n = 0; n < 8; n++)
        out4[(size_t)(node0 + ng * 8 + n) * (NHID / 4) + hg] = acc[n];
}

__global__ __launch_bounds__(256) void scatter_edges(const int* __restrict__ ei,
                                                     const float* __restrict__ ew,
                                                     const float* __restrict__ support,
                                                     float* __restrict__ out) {
    const int tid  = threadIdx.x;
    const int lane = tid & 31;
    const int e    = blockIdx.x * 8 + (tid >> 5);
    const int   src = ei[e];
    const int   dst = ei[NEDGES + e];
    const float w   = ew[e];
    const float4* s4 = (const float4*)support;
    float4 v = s4[(size_t)src * (NHID / 4) + lane];
    float* o = out + (size_t)dst * NHID + lane * 4;
    atomicAdd(o + 0, v.x * w);
    atomicAdd(o + 1, v.y * w);
    atomicAdd(o + 2, v.z * w);
    atomicAdd(o + 3, v.w * w);
}

__global__ __launch_bounds__(256) void finalize(float* __restrict__ out,
                                                const float* __restrict__ b) {
    const int i = blockIdx.x * 256 + threadIdx.x;
    float4*       o4 = (float4*)out;
    const float4* b4 = (const float4*)b;
    float4 v  = o4[i];
    float4 bb = b4[i & 31];
    v.x = fmaxf(v.x + bb.x, 0.f);
    v.y = fmaxf(v.y + bb.y, 0.f);
    v.z = fmaxf(v.z + bb.z, 0.f);
    v.w = fmaxf(v.w + bb.w, 0.f);
    o4[i] = v;
}

extern "C" void kernel_launch(void* const* d_in, const int* in_sizes, int n_in,
                              void* d_out, int out_size, void* d_ws, size_t ws_size,
                              hipStream_t stream) {
    const float* x  = (const float*)d_in[0];
    const int*   ei = (const int*)d_in[1];
    const float* ew = (const float*)d_in[2];
    const float* W  = (const float*)d_in[3];
    const float* b  = (const float*)d_in[4];
    float*       out = (float*)d_out;

    char* ws = (char*)d_ws;

    if (ws_size >= WS_NEEDED) {
        unsigned short*     support = (unsigned short*)(ws + SUP_OFF);
        unsigned short*     Wt      = (unsigned short*)(ws + WT_OFF);
        unsigned int*       rcur    = (unsigned int*)(ws + RC_OFF);
        unsigned long long* ebin    = (unsigned long long*)(ws + EBIN_OFF);

        setup_wt_cur<<<160, 256, 0, stream>>>(W, Wt, rcur);
        gemm_fill<<<GEMM_BLOCKS + PARTB, 256, 0, stream>>>(
            x, Wt, support, ei, ew, rcur, ebin);
        gather_range<<<NR, 512, 0, stream>>>(rcur, ebin, support, b, out);
    } else {
        float* support = (float*)(ws + SUP_OFF);
        gemm_xw<<<NNODES / 64, 256, 0, stream>>>(x, W, support);
        hipMemsetAsync(d_out, 0, (size_t)out_size * sizeof(float), stream);
        scatter_edges<<<NEDGES / 8, 256, 0, stream>>>(ei, ew, support, out);
        finalize<<<out_size / 4 / 256, 256, 0, stream>>>(out, b);
    }
}

// Round 8
// 157.772 us; speedup vs baseline: 5.2372x; 5.2372x over previous
//
#include <hip/hip_runtime.h>

#define NNODES 40000
#define NEDGES 640000
#define NFEAT  256
#define NHID   128

// ---- range partition geometry ----
#define RSHIFT 7                        // 128 nodes per range
#define RNODES 128
#define NR     313                      // ceil(40000/128)
#define CAPR   3000                     // slots per range; E[count]=2048, 21 sigma margin
#define PARTB  250                      // partition blocks
#define EPB    2560                     // edges per partition block (10/thread)
#define GEMM_BLOCKS (NNODES / 64)       // 625

// ---- workspace layout (bytes) ----
#define SUP_OFF  0u                     // support bf16: 40000*128*2 = 10,240,000
#define WT_OFF   10240000u              // Wt bf16: 128*256*2 = 65,536
#define RC_OFF   10305536u              // range_cursor: 313 u32 (padded)
#define EBIN_OFF 10307584u              // ebin: 313*3000*8 = 7,512,000 -> ends 17,819,584
#define WS_NEEDED 18145536u             // unchanged gate (fits)

typedef float floatx4 __attribute__((ext_vector_type(4)));
typedef __bf16 bf16x8 __attribute__((ext_vector_type(8)));
typedef unsigned short ushort8 __attribute__((ext_vector_type(8)));
union BfFrag { ushort8 s; bf16x8 b; };

__device__ __forceinline__ unsigned short f2bf(float f) {
    unsigned int u = __float_as_uint(f);
    u = (u + 0x7FFFu + ((u >> 16) & 1u)) >> 16;   // RNE
    return (unsigned short)u;
}

// decode 2x(2 bf16) -> float4
__device__ __forceinline__ float4 bf4(unsigned int lo, unsigned int hi) {
    float4 v;
    v.x = __uint_as_float(lo << 16);
    v.y = __uint_as_float(lo & 0xFFFF0000u);
    v.z = __uint_as_float(hi << 16);
    v.w = __uint_as_float(hi & 0xFFFF0000u);
    return v;
}

// ---------------------------------------------------------------------------
// K0: setup — zero range_cursor AND Wt[h][k] = bf16(W[k][h]).
// ---------------------------------------------------------------------------
__global__ __launch_bounds__(256) void setup_wt_cur(const float* __restrict__ W,
                                                    unsigned short* __restrict__ Wt,
                                                    unsigned int* __restrict__ range_cursor) {
    const int i = blockIdx.x * 256 + threadIdx.x;
    if (i < NR) range_cursor[i] = 0;
    if (i < NFEAT * NHID) {
        const int h = i >> 8;
        const int k = i & 255;
        Wt[i] = f2bf(W[k * NHID + h]);
    }
}

// ---------------------------------------------------------------------------
// K1: GEMM (blocks [0,625)) || edge partition (blocks [625,875)).
// Partition: LDS histogram over 313 dst-ranges -> ~300 global atomics/block
// -> LDS-grouped staging -> CONTIGUOUS-run writes of 8B records into
// per-range bins. (R6: removed gemm_fill from the top-5 — the 640k random
// 4B stores / line writebacks were the R0-R4 fill wall.)
// ---------------------------------------------------------------------------
__global__ __launch_bounds__(256) void gemm_fill(const float* __restrict__ x,
                                                 const unsigned short* __restrict__ Wt,
                                                 unsigned short* __restrict__ support,
                                                 const int* __restrict__ ei,
                                                 const float* __restrict__ ew,
                                                 unsigned int* __restrict__ range_cursor,
                                                 unsigned long long* __restrict__ ebin) {
    const int tid = threadIdx.x;

    if (blockIdx.x >= GEMM_BLOCKS) {
        // ---- partition path ----
        __shared__ unsigned int hist[320];
        __shared__ unsigned int sA[320], sB[320];
        __shared__ unsigned int lstart[320];
        __shared__ unsigned int gbase[320];
        __shared__ unsigned int ldscur[320];
        __shared__ unsigned long long recbuf[EPB];
        __shared__ unsigned short rbuf[EPB];

        const int pb   = blockIdx.x - GEMM_BLOCKS;
        const int base = pb * EPB + tid;

        for (int i = tid; i < 320; i += 256) { hist[i] = 0; ldscur[i] = 0; }
        __syncthreads();

        // pass 1: histogram dst ranges
        int dst[10];
        #pragma unroll
        for (int j = 0; j < 10; j++) dst[j] = ei[NEDGES + base + j * 256];
        #pragma unroll
        for (int j = 0; j < 10; j++) atomicAdd(&hist[dst[j] >> RSHIFT], 1u);
        __syncthreads();

        // exclusive scan of hist (Hillis-Steele over 320, 9 passes)
        for (int i = tid; i < 320; i += 256) sA[i] = (i > 0) ? hist[i - 1] : 0u;
        __syncthreads();
        unsigned int* cur = sA;
        unsigned int* nxt = sB;
        for (int off = 1; off < 320; off <<= 1) {
            for (int i = tid; i < 320; i += 256)
                nxt[i] = cur[i] + ((i >= off) ? cur[i - off] : 0u);
            __syncthreads();
            unsigned int* t = cur; cur = nxt; nxt = t;
        }
        for (int i = tid; i < 320; i += 256) {
            lstart[i] = cur[i];
            gbase[i]  = (i < NR && hist[i] > 0u)
                        ? atomicAdd(&range_cursor[i], hist[i]) : 0u;
        }
        __syncthreads();

        // pass 2: stage records grouped by range
        int src[10];
        float w[10];
        #pragma unroll
        for (int j = 0; j < 10; j++) {
            src[j] = ei[base + j * 256];
            w[j]   = ew[base + j * 256];
        }
        #pragma unroll
        for (int j = 0; j < 10; j++) {
            const int r  = dst[j] >> RSHIFT;
            const unsigned int lr = atomicAdd(&ldscur[r], 1u);
            const unsigned int pos = lstart[r] + lr;
            recbuf[pos] = ((unsigned long long)f2bf(w[j]) << 32)
                        | ((unsigned long long)(dst[j] & (RNODES - 1)) << 16)
                        | (unsigned long long)(unsigned int)src[j];
            rbuf[pos] = (unsigned short)r;
        }
        __syncthreads();

        // writeout: consecutive staging entries of a range -> consecutive slots
        for (int i = tid; i < EPB; i += 256) {
            const int r = rbuf[i];
            const unsigned int slot = gbase[r] + ((unsigned int)i - lstart[r]);
            if (slot < CAPR)
                ebin[(size_t)r * CAPR + slot] = recbuf[i];
        }
        return;
    }

    // ---- GEMM path (unchanged) ----
    const int lane = tid & 63;
    const int wv   = tid >> 6;
    const int m    = lane & 15;
    const int quad = lane >> 4;
    const int node = blockIdx.x * 64 + wv * 16 + m;

    BfFrag afrag[8];
    const float* xrow = x + (size_t)node * NFEAT + quad * 8;
    #pragma unroll
    for (int ks = 0; ks < 8; ks++) {
        float4 f0 = *(const float4*)(xrow + ks * 32);
        float4 f1 = *(const float4*)(xrow + ks * 32 + 4);
        afrag[ks].s[0] = f2bf(f0.x); afrag[ks].s[1] = f2bf(f0.y);
        afrag[ks].s[2] = f2bf(f0.z); afrag[ks].s[3] = f2bf(f0.w);
        afrag[ks].s[4] = f2bf(f1.x); afrag[ks].s[5] = f2bf(f1.y);
        afrag[ks].s[6] = f2bf(f1.z); afrag[ks].s[7] = f2bf(f1.w);
    }

    floatx4 acc[8];
    #pragma unroll
    for (int nt = 0; nt < 8; nt++) acc[nt] = (floatx4){0.f, 0.f, 0.f, 0.f};

    #pragma unroll
    for (int nt = 0; nt < 8; nt++) {
        const unsigned short* wrow = Wt + (size_t)(nt * 16 + m) * NFEAT + quad * 8;
        #pragma unroll
        for (int ks = 0; ks < 8; ks++) {
            BfFrag bfrag;
            bfrag.s = *(const ushort8*)(wrow + ks * 32);
            acc[nt] = __builtin_amdgcn_mfma_f32_16x16x32_bf16(afrag[ks].b, bfrag.b,
                                                              acc[nt], 0, 0, 0);
        }
    }

    const int row0 = blockIdx.x * 64 + wv * 16 + quad * 4;
    #pragma unroll
    for (int nt = 0; nt < 8; nt++) {
        #pragma unroll
        for (int r = 0; r < 4; r++) {
            support[(size_t)(row0 + r) * NHID + nt * 16 + m] = f2bf(acc[nt][r]);
        }
    }
}

// ---------------------------------------------------------------------------
// K2: gather — one block (512 thr) per dst-range. NO fp atomics (R6/R7's
// 700us wall was LDS fp32 atomicAdd lowering to a CAS loop: duration was
// structure-invariant, everything idle). Instead:
//   1) histogram dl via native u32 LDS atomics (~2k ops)
//   2) 7-pass exclusive scan over 128
//   3) scatter records into dl-SORTED LDS buffer (24KB)
//   4) 4-lane group per node: walk its ~16 sorted records, 4x uint4
//      support-row load per lane (group = 256B contiguous), REGISTER
//      accumulation of 32 hids/lane, bias+relu+store direct.
// 128 independent 4-lane streams/block provide MLP; no epilogue pass.
// ---------------------------------------------------------------------------
__global__ __launch_bounds__(512) void gather_range(
        const unsigned int* __restrict__ range_cursor,
        const unsigned long long* __restrict__ ebin,
        const unsigned short* __restrict__ support,
        const float* __restrict__ b,
        float* __restrict__ out) {
    __shared__ unsigned long long srec[CAPR];        // 24000 B, dl-sorted records
    __shared__ unsigned int hcnt[RNODES];            // histogram, then scatter cursor
    __shared__ unsigned int hstart[RNODES + 1];
    __shared__ unsigned int sA[RNODES], sB[RNODES];

    const int r   = blockIdx.x;
    const int tid = threadIdx.x;

    unsigned int cnt = range_cursor[r];
    if (cnt > CAPR) cnt = CAPR;
    const unsigned long long* bin = ebin + (size_t)r * CAPR;

    if (tid < RNODES) hcnt[tid] = 0u;
    __syncthreads();

    // 1) histogram dl (u32 LDS atomics — native ds_add_rtn_u32)
    for (unsigned int i = tid; i < cnt; i += 512)
        atomicAdd(&hcnt[(unsigned int)(bin[i] >> 16) & (RNODES - 1)], 1u);
    __syncthreads();

    // 2) exclusive scan over 128 (Hillis-Steele, 7 passes)
    if (tid < RNODES) sA[tid] = (tid > 0) ? hcnt[tid - 1] : 0u;
    __syncthreads();
    unsigned int* cur = sA;
    unsigned int* nxt = sB;
    for (int off = 1; off < RNODES; off <<= 1) {
        if (tid < RNODES) nxt[tid] = cur[tid] + ((tid >= off) ? cur[tid - off] : 0u);
        __syncthreads();
        unsigned int* t = cur; cur = nxt; nxt = t;
    }
    if (tid < RNODES) { hstart[tid] = cur[tid]; hcnt[tid] = cur[tid]; }
    if (tid == 0) hstart[RNODES] = cnt;
    __syncthreads();

    // 3) scatter into sorted order
    for (unsigned int i = tid; i < cnt; i += 512) {
        const unsigned long long rec = bin[i];
        const unsigned int dl = (unsigned int)(rec >> 16) & (RNODES - 1);
        const unsigned int p  = atomicAdd(&hcnt[dl], 1u);
        srec[p] = rec;
    }
    __syncthreads();

    // 4) register-accumulated gather: 4 lanes per node, 32 hids per lane
    const int nl = tid >> 2;            // node-local 0..127
    const int j  = tid & 3;             // hid slice: [32j, 32j+32)
    const unsigned int kb = hstart[nl];
    const unsigned int ke = hstart[nl + 1];

    float acc[32];
    #pragma unroll
    for (int t = 0; t < 32; t++) acc[t] = 0.f;

    const uint4* sup4 = (const uint4*)support;       // 16 uint4 per row
    #pragma unroll 2
    for (unsigned int k = kb; k < ke; ++k) {
        const unsigned long long rec = srec[k];      // broadcast in 4-lane group
        const float w  = __uint_as_float(((unsigned int)(rec >> 32)) << 16);
        const int   sc = (int)(rec & 0xFFFFu);
        const uint4* rowp = sup4 + (size_t)sc * 16 + (j << 2);
        const uint4 u0 = rowp[0];
        const uint4 u1 = rowp[1];
        const uint4 u2 = rowp[2];
        const uint4 u3 = rowp[3];
        float4 v;
        v = bf4(u0.x, u0.y); acc[0] += w*v.x;  acc[1] += w*v.y;  acc[2] += w*v.z;  acc[3] += w*v.w;
        v = bf4(u0.z, u0.w); acc[4] += w*v.x;  acc[5] += w*v.y;  acc[6] += w*v.z;  acc[7] += w*v.w;
        v = bf4(u1.x, u1.y); acc[8] += w*v.x;  acc[9] += w*v.y;  acc[10] += w*v.z; acc[11] += w*v.w;
        v = bf4(u1.z, u1.w); acc[12] += w*v.x; acc[13] += w*v.y; acc[14] += w*v.z; acc[15] += w*v.w;
        v = bf4(u2.x, u2.y); acc[16] += w*v.x; acc[17] += w*v.y; acc[18] += w*v.z; acc[19] += w*v.w;
        v = bf4(u2.z, u2.w); acc[20] += w*v.x; acc[21] += w*v.y; acc[22] += w*v.z; acc[23] += w*v.w;
        v = bf4(u3.x, u3.y); acc[24] += w*v.x; acc[25] += w*v.y; acc[26] += w*v.z; acc[27] += w*v.w;
        v = bf4(u3.z, u3.w); acc[28] += w*v.x; acc[29] += w*v.y; acc[30] += w*v.z; acc[31] += w*v.w;
    }

    // epilogue: bias + relu + direct store (no extra pass)
    const int node = r * RNODES + nl;
    if (node < NNODES) {
        const float4* b4p = (const float4*)b + (j << 3);
        float4*       o4  = (float4*)out + (size_t)node * (NHID / 4) + (j << 3);
        #pragma unroll
        for (int t = 0; t < 8; t++) {
            float4 bb = b4p[t];
            float4 v;
            v.x = fmaxf(acc[t * 4 + 0] + bb.x, 0.f);
            v.y = fmaxf(acc[t * 4 + 1] + bb.y, 0.f);
            v.z = fmaxf(acc[t * 4 + 2] + bb.z, 0.f);
            v.w = fmaxf(acc[t * 4 + 3] + bb.w, 0.f);
            o4[t] = v;
        }
    }
}

// ---------------------------------------------------------------------------
// Fallback path (ws too small): fp32 GEMM + atomic scatter
// ---------------------------------------------------------------------------
__global__ __launch_bounds__(256) void gemm_xw(const float* __restrict__ x,
                                               const float* __restrict__ W,
                                               float* __restrict__ support) {
    __shared__ float xs[64 * NFEAT];
    const int tid   = threadIdx.x;
    const int node0 = blockIdx.x * 64;

    const float4* xg  = (const float4*)(x + (size_t)node0 * NFEAT);
    float4*       xs4 = (float4*)xs;
    #pragma unroll
    for (int i = tid; i < 64 * (NFEAT / 4); i += 256) xs4[i] = xg[i];
    __syncthreads();

    const int hg = tid & 31;
    const int ng = tid >> 5;
    const float4* W4 = (const float4*)W;

    float4 acc[8];
    #pragma unroll
    for (int n = 0; n < 8; n++) acc[n] = make_float4(0.f, 0.f, 0.f, 0.f);

    #pragma unroll 4
    for (int k = 0; k < NFEAT; k++) {
        float4 w = W4[k * (NHID / 4) + hg];
        #pragma unroll
        for (int n = 0; n < 8; n++) {
            float xv = xs[(ng * 8 + n) * NFEAT + k];
            acc[n].x = fmaf(xv, w.x, acc[n].x);
            acc[n].y = fmaf(xv, w.y, acc[n].y);
            acc[n].z = fmaf(xv, w.z, acc[n].z);
            acc[n].w = fmaf(xv, w.w, acc[n].w);
        }
    }

    float4* out4 = (float4*)support;
    #pragma unroll
    for (int n = 0; n < 8; n++)
        out4[(size_t)(node0 + ng * 8 + n) * (NHID / 4) + hg] = acc[n];
}

__global__ __launch_bounds__(256) void scatter_edges(const int* __restrict__ ei,
                                                     const float* __restrict__ ew,
                                                     const float* __restrict__ support,
                                                     float* __restrict__ out) {
    const int tid  = threadIdx.x;
    const int lane = tid & 31;
    const int e    = blockIdx.x * 8 + (tid >> 5);
    const int   src = ei[e];
    const int   dst = ei[NEDGES + e];
    const float w   = ew[e];
    const float4* s4 = (const float4*)support;
    float4 v = s4[(size_t)src * (NHID / 4) + lane];
    float* o = out + (size_t)dst * NHID + lane * 4;
    atomicAdd(o + 0, v.x * w);
    atomicAdd(o + 1, v.y * w);
    atomicAdd(o + 2, v.z * w);
    atomicAdd(o + 3, v.w * w);
}

__global__ __launch_bounds__(256) void finalize(float* __restrict__ out,
                                                const float* __restrict__ b) {
    const int i = blockIdx.x * 256 + threadIdx.x;
    float4*       o4 = (float4*)out;
    const float4* b4 = (const float4*)b;
    float4 v  = o4[i];
    float4 bb = b4[i & 31];
    v.x = fmaxf(v.x + bb.x, 0.f);
    v.y = fmaxf(v.y + bb.y, 0.f);
    v.z = fmaxf(v.z + bb.z, 0.f);
    v.w = fmaxf(v.w + bb.w, 0.f);
    o4[i] = v;
}

extern "C" void kernel_launch(void* const* d_in, const int* in_sizes, int n_in,
                              void* d_out, int out_size, void* d_ws, size_t ws_size,
                              hipStream_t stream) {
    const float* x  = (const float*)d_in[0];
    const int*   ei = (const int*)d_in[1];
    const float* ew = (const float*)d_in[2];
    const float* W  = (const float*)d_in[3];
    const float* b  = (const float*)d_in[4];
    float*       out = (float*)d_out;

    char* ws = (char*)d_ws;

    if (ws_size >= WS_NEEDED) {
        unsigned short*     support = (unsigned short*)(ws + SUP_OFF);
        unsigned short*     Wt      = (unsigned short*)(ws + WT_OFF);
        unsigned int*       rcur    = (unsigned int*)(ws + RC_OFF);
        unsigned long long* ebin    = (unsigned long long*)(ws + EBIN_OFF);

        setup_wt_cur<<<160, 256, 0, stream>>>(W, Wt, rcur);
        gemm_fill<<<GEMM_BLOCKS + PARTB, 256, 0, stream>>>(
            x, Wt, support, ei, ew, rcur, ebin);
        gather_range<<<NR, 512, 0, stream>>>(rcur, ebin, support, b, out);
    } else {
        float* support = (float*)(ws + SUP_OFF);
        gemm_xw<<<NNODES / 64, 256, 0, stream>>>(x, W, support);
        hipMemsetAsync(d_out, 0, (size_t)out_size * sizeof(float), stream);
        scatter_edges<<<NEDGES / 8, 256, 0, stream>>>(ei, ew, support, out);
        finalize<<<out_size / 4 / 256, 256, 0, stream>>>(out, b);
    }
}

// Round 9
// 151.936 us; speedup vs baseline: 5.4383x; 1.0384x over previous
//
#include <hip/hip_runtime.h>

#define NNODES 40000
#define NEDGES 640000
#define NFEAT  256
#define NHID   128

// ---- range partition geometry ----
#define RSHIFT 7                        // 128 nodes per range
#define RNODES 128
#define NR     313                      // ceil(40000/128)
#define CAPR   3000                     // slots per range; E[count]=2048, 21 sigma margin
#define PARTB  250                      // partition blocks
#define EPB    2560                     // edges per partition block (10/thread)
#define GEMM_BLOCKS (NNODES / 64)       // 625

// ---- workspace layout (bytes) ----
#define SUP_OFF  0u                     // support bf16: 40000*128*2 = 10,240,000
#define WT_OFF   10240000u              // Wt bf16: 128*256*2 = 65,536
#define RC_OFF   10305536u              // range_cursor: 313 u32 (padded)
#define EBIN_OFF 10307584u              // ebin: 313*3000*8 = 7,512,000 -> ends 17,819,584
#define WS_NEEDED 18145536u             // unchanged gate (fits)

typedef float floatx4 __attribute__((ext_vector_type(4)));
typedef __bf16 bf16x8 __attribute__((ext_vector_type(8)));
typedef unsigned short ushort8 __attribute__((ext_vector_type(8)));
union BfFrag { ushort8 s; bf16x8 b; };

__device__ __forceinline__ unsigned short f2bf(float f) {
    unsigned int u = __float_as_uint(f);
    u = (u + 0x7FFFu + ((u >> 16) & 1u)) >> 16;   // RNE
    return (unsigned short)u;
}

// decode 2x(2 bf16) -> float4
__device__ __forceinline__ float4 bf4(unsigned int lo, unsigned int hi) {
    float4 v;
    v.x = __uint_as_float(lo << 16);
    v.y = __uint_as_float(lo & 0xFFFF0000u);
    v.z = __uint_as_float(hi << 16);
    v.w = __uint_as_float(hi & 0xFFFF0000u);
    return v;
}

// ---------------------------------------------------------------------------
// K0: setup — zero range_cursor AND Wt[h][k] = bf16(W[k][h]).
// ---------------------------------------------------------------------------
__global__ __launch_bounds__(256) void setup_wt_cur(const float* __restrict__ W,
                                                    unsigned short* __restrict__ Wt,
                                                    unsigned int* __restrict__ range_cursor) {
    const int i = blockIdx.x * 256 + threadIdx.x;
    if (i < NR) range_cursor[i] = 0;
    if (i < NFEAT * NHID) {
        const int h = i >> 8;
        const int k = i & 255;
        Wt[i] = f2bf(W[k * NHID + h]);
    }
}

// ---------------------------------------------------------------------------
// K1: GEMM (blocks [0,625)) || edge partition (blocks [625,875)).
// R8 lesson: the partition branch's 33KB static LDS was charged to EVERY
// block (incl. 625 GEMM blocks) -> 4 blocks/CU, 24% occ, latency-bound.
// Compressed staging: (r<<7)|dl == dst fits a USHORT, so stage
// {wsrc u32 = bf16(w)<<16|src, dstb u16 = dst} instead of 8B rec + 2B tag:
// LDS 33KB -> 22.5KB -> 7 blocks/CU. Same algorithm otherwise.
// ---------------------------------------------------------------------------
__global__ __launch_bounds__(256) void gemm_fill(const float* __restrict__ x,
                                                 const unsigned short* __restrict__ Wt,
                                                 unsigned short* __restrict__ support,
                                                 const int* __restrict__ ei,
                                                 const float* __restrict__ ew,
                                                 unsigned int* __restrict__ range_cursor,
                                                 unsigned long long* __restrict__ ebin) {
    const int tid = threadIdx.x;

    if (blockIdx.x >= GEMM_BLOCKS) {
        // ---- partition path ----
        __shared__ unsigned int hist[320];
        __shared__ unsigned int sA[320], sB[320];
        __shared__ unsigned int lstart[320];
        __shared__ unsigned int gbase[320];
        __shared__ unsigned int ldscur[320];
        __shared__ unsigned int wsrc[EPB];           // 10240 B
        __shared__ unsigned short dstb[EPB];         // 5120 B

        const int pb   = blockIdx.x - GEMM_BLOCKS;
        const int base = pb * EPB + tid;

        for (int i = tid; i < 320; i += 256) { hist[i] = 0; ldscur[i] = 0; }
        __syncthreads();

        // pass 1: histogram dst ranges
        int dst[10];
        #pragma unroll
        for (int j = 0; j < 10; j++) dst[j] = ei[NEDGES + base + j * 256];
        #pragma unroll
        for (int j = 0; j < 10; j++) atomicAdd(&hist[dst[j] >> RSHIFT], 1u);
        __syncthreads();

        // exclusive scan of hist (Hillis-Steele over 320, 9 passes)
        for (int i = tid; i < 320; i += 256) sA[i] = (i > 0) ? hist[i - 1] : 0u;
        __syncthreads();
        unsigned int* cur = sA;
        unsigned int* nxt = sB;
        for (int off = 1; off < 320; off <<= 1) {
            for (int i = tid; i < 320; i += 256)
                nxt[i] = cur[i] + ((i >= off) ? cur[i - off] : 0u);
            __syncthreads();
            unsigned int* t = cur; cur = nxt; nxt = t;
        }
        for (int i = tid; i < 320; i += 256) {
            lstart[i] = cur[i];
            gbase[i]  = (i < NR && hist[i] > 0u)
                        ? atomicAdd(&range_cursor[i], hist[i]) : 0u;
        }
        __syncthreads();

        // pass 2: stage records grouped by range (compressed: 6B/record)
        int src[10];
        float w[10];
        #pragma unroll
        for (int j = 0; j < 10; j++) {
            src[j] = ei[base + j * 256];
            w[j]   = ew[base + j * 256];
        }
        #pragma unroll
        for (int j = 0; j < 10; j++) {
            const int r  = dst[j] >> RSHIFT;
            const unsigned int lr = atomicAdd(&ldscur[r], 1u);
            const unsigned int pos = lstart[r] + lr;
            wsrc[pos] = ((unsigned int)f2bf(w[j]) << 16) | (unsigned int)src[j];
            dstb[pos] = (unsigned short)dst[j];
        }
        __syncthreads();

        // writeout: consecutive staging entries of a range -> consecutive slots
        for (int i = tid; i < EPB; i += 256) {
            const unsigned int d  = dstb[i];
            const unsigned int r  = d >> RSHIFT;
            const unsigned int slot = gbase[r] + ((unsigned int)i - lstart[r]);
            if (slot < CAPR) {
                const unsigned int ws = wsrc[i];
                const unsigned long long rec =
                    ((unsigned long long)(ws >> 16) << 32)
                  | ((unsigned long long)(d & (RNODES - 1)) << 16)
                  | (unsigned long long)(ws & 0xFFFFu);
                ebin[(size_t)r * CAPR + slot] = rec;
            }
        }
        return;
    }

    // ---- GEMM path (unchanged) ----
    const int lane = tid & 63;
    const int wv   = tid >> 6;
    const int m    = lane & 15;
    const int quad = lane >> 4;
    const int node = blockIdx.x * 64 + wv * 16 + m;

    BfFrag afrag[8];
    const float* xrow = x + (size_t)node * NFEAT + quad * 8;
    #pragma unroll
    for (int ks = 0; ks < 8; ks++) {
        float4 f0 = *(const float4*)(xrow + ks * 32);
        float4 f1 = *(const float4*)(xrow + ks * 32 + 4);
        afrag[ks].s[0] = f2bf(f0.x); afrag[ks].s[1] = f2bf(f0.y);
        afrag[ks].s[2] = f2bf(f0.z); afrag[ks].s[3] = f2bf(f0.w);
        afrag[ks].s[4] = f2bf(f1.x); afrag[ks].s[5] = f2bf(f1.y);
        afrag[ks].s[6] = f2bf(f1.z); afrag[ks].s[7] = f2bf(f1.w);
    }

    floatx4 acc[8];
    #pragma unroll
    for (int nt = 0; nt < 8; nt++) acc[nt] = (floatx4){0.f, 0.f, 0.f, 0.f};

    #pragma unroll
    for (int nt = 0; nt < 8; nt++) {
        const unsigned short* wrow = Wt + (size_t)(nt * 16 + m) * NFEAT + quad * 8;
        #pragma unroll
        for (int ks = 0; ks < 8; ks++) {
            BfFrag bfrag;
            bfrag.s = *(const ushort8*)(wrow + ks * 32);
            acc[nt] = __builtin_amdgcn_mfma_f32_16x16x32_bf16(afrag[ks].b, bfrag.b,
                                                              acc[nt], 0, 0, 0);
        }
    }

    const int row0 = blockIdx.x * 64 + wv * 16 + quad * 4;
    #pragma unroll
    for (int nt = 0; nt < 8; nt++) {
        #pragma unroll
        for (int r = 0; r < 4; r++) {
            support[(size_t)(row0 + r) * NHID + nt * 16 + m] = f2bf(acc[nt][r]);
        }
    }
}

// ---------------------------------------------------------------------------
// K2: gather — one block (512 thr) per dst-range. NO fp atomics (R6/R7's
// 700us wall was LDS fp32 atomicAdd lowering to a CAS loop). Proven in R8
// at <43us:
//   1) histogram dl via native u32 LDS atomics
//   2) 7-pass exclusive scan over 128
//   3) scatter records into dl-SORTED LDS buffer (24KB)
//   4) 4-lane group per node: walk its ~16 sorted records, 4x uint4
//      support-row load per lane (group = 256B contiguous), REGISTER
//      accumulation of 32 hids/lane, bias+relu+store direct.
// ---------------------------------------------------------------------------
__global__ __launch_bounds__(512) void gather_range(
        const unsigned int* __restrict__ range_cursor,
        const unsigned long long* __restrict__ ebin,
        const unsigned short* __restrict__ support,
        const float* __restrict__ b,
        float* __restrict__ out) {
    __shared__ unsigned long long srec[CAPR];        // 24000 B, dl-sorted records
    __shared__ unsigned int hcnt[RNODES];            // histogram, then scatter cursor
    __shared__ unsigned int hstart[RNODES + 1];
    __shared__ unsigned int sA[RNODES], sB[RNODES];

    const int r   = blockIdx.x;
    const int tid = threadIdx.x;

    unsigned int cnt = range_cursor[r];
    if (cnt > CAPR) cnt = CAPR;
    const unsigned long long* bin = ebin + (size_t)r * CAPR;

    if (tid < RNODES) hcnt[tid] = 0u;
    __syncthreads();

    // 1) histogram dl (u32 LDS atomics — native)
    for (unsigned int i = tid; i < cnt; i += 512)
        atomicAdd(&hcnt[(unsigned int)(bin[i] >> 16) & (RNODES - 1)], 1u);
    __syncthreads();

    // 2) exclusive scan over 128 (Hillis-Steele, 7 passes)
    if (tid < RNODES) sA[tid] = (tid > 0) ? hcnt[tid - 1] : 0u;
    __syncthreads();
    unsigned int* cur = sA;
    unsigned int* nxt = sB;
    for (int off = 1; off < RNODES; off <<= 1) {
        if (tid < RNODES) nxt[tid] = cur[tid] + ((tid >= off) ? cur[tid - off] : 0u);
        __syncthreads();
        unsigned int* t = cur; cur = nxt; nxt = t;
    }
    if (tid < RNODES) { hstart[tid] = cur[tid]; hcnt[tid] = cur[tid]; }
    if (tid == 0) hstart[RNODES] = cnt;
    __syncthreads();

    // 3) scatter into sorted order
    for (unsigned int i = tid; i < cnt; i += 512) {
        const unsigned long long rec = bin[i];
        const unsigned int dl = (unsigned int)(rec >> 16) & (RNODES - 1);
        const unsigned int p  = atomicAdd(&hcnt[dl], 1u);
        srec[p] = rec;
    }
    __syncthreads();

    // 4) register-accumulated gather: 4 lanes per node, 32 hids per lane
    const int nl = tid >> 2;            // node-local 0..127
    const int j  = tid & 3;             // hid slice: [32j, 32j+32)
    const unsigned int kb = hstart[nl];
    const unsigned int ke = hstart[nl + 1];

    float acc[32];
    #pragma unroll
    for (int t = 0; t < 32; t++) acc[t] = 0.f;

    const uint4* sup4 = (const uint4*)support;       // 16 uint4 per row
    #pragma unroll 2
    for (unsigned int k = kb; k < ke; ++k) {
        const unsigned long long rec = srec[k];      // broadcast in 4-lane group
        const float w  = __uint_as_float(((unsigned int)(rec >> 32)) << 16);
        const int   sc = (int)(rec & 0xFFFFu);
        const uint4* rowp = sup4 + (size_t)sc * 16 + (j << 2);
        const uint4 u0 = rowp[0];
        const uint4 u1 = rowp[1];
        const uint4 u2 = rowp[2];
        const uint4 u3 = rowp[3];
        float4 v;
        v = bf4(u0.x, u0.y); acc[0] += w*v.x;  acc[1] += w*v.y;  acc[2] += w*v.z;  acc[3] += w*v.w;
        v = bf4(u0.z, u0.w); acc[4] += w*v.x;  acc[5] += w*v.y;  acc[6] += w*v.z;  acc[7] += w*v.w;
        v = bf4(u1.x, u1.y); acc[8] += w*v.x;  acc[9] += w*v.y;  acc[10] += w*v.z; acc[11] += w*v.w;
        v = bf4(u1.z, u1.w); acc[12] += w*v.x; acc[13] += w*v.y; acc[14] += w*v.z; acc[15] += w*v.w;
        v = bf4(u2.x, u2.y); acc[16] += w*v.x; acc[17] += w*v.y; acc[18] += w*v.z; acc[19] += w*v.w;
        v = bf4(u2.z, u2.w); acc[20] += w*v.x; acc[21] += w*v.y; acc[22] += w*v.z; acc[23] += w*v.w;
        v = bf4(u3.x, u3.y); acc[24] += w*v.x; acc[25] += w*v.y; acc[26] += w*v.z; acc[27] += w*v.w;
        v = bf4(u3.z, u3.w); acc[28] += w*v.x; acc[29] += w*v.y; acc[30] += w*v.z; acc[31] += w*v.w;
    }

    // epilogue: bias + relu + direct store (no extra pass)
    const int node = r * RNODES + nl;
    if (node < NNODES) {
        const float4* b4p = (const float4*)b + (j << 3);
        float4*       o4  = (float4*)out + (size_t)node * (NHID / 4) + (j << 3);
        #pragma unroll
        for (int t = 0; t < 8; t++) {
            float4 bb = b4p[t];
            float4 v;
            v.x = fmaxf(acc[t * 4 + 0] + bb.x, 0.f);
            v.y = fmaxf(acc[t * 4 + 1] + bb.y, 0.f);
            v.z = fmaxf(acc[t * 4 + 2] + bb.z, 0.f);
            v.w = fmaxf(acc[t * 4 + 3] + bb.w, 0.f);
            o4[t] = v;
        }
    }
}

// ---------------------------------------------------------------------------
// Fallback path (ws too small): fp32 GEMM + atomic scatter
// ---------------------------------------------------------------------------
__global__ __launch_bounds__(256) void gemm_xw(const float* __restrict__ x,
                                               const float* __restrict__ W,
                                               float* __restrict__ support) {
    __shared__ float xs[64 * NFEAT];
    const int tid   = threadIdx.x;
    const int node0 = blockIdx.x * 64;

    const float4* xg  = (const float4*)(x + (size_t)node0 * NFEAT);
    float4*       xs4 = (float4*)xs;
    #pragma unroll
    for (int i = tid; i < 64 * (NFEAT / 4); i += 256) xs4[i] = xg[i];
    __syncthreads();

    const int hg = tid & 31;
    const int ng = tid >> 5;
    const float4* W4 = (const float4*)W;

    float4 acc[8];
    #pragma unroll
    for (int n = 0; n < 8; n++) acc[n] = make_float4(0.f, 0.f, 0.f, 0.f);

    #pragma unroll 4
    for (int k = 0; k < NFEAT; k++) {
        float4 w = W4[k * (NHID / 4) + hg];
        #pragma unroll
        for (int n = 0; n < 8; n++) {
            float xv = xs[(ng * 8 + n) * NFEAT + k];
            acc[n].x = fmaf(xv, w.x, acc[n].x);
            acc[n].y = fmaf(xv, w.y, acc[n].y);
            acc[n].z = fmaf(xv, w.z, acc[n].z);
            acc[n].w = fmaf(xv, w.w, acc[n].w);
        }
    }

    float4* out4 = (float4*)support;
    #pragma unroll
    for (int n = 0; n < 8; n++)
        out4[(size_t)(node0 + ng * 8 + n) * (NHID / 4) + hg] = acc[n];
}

__global__ __launch_bounds__(256) void scatter_edges(const int* __restrict__ ei,
                                                     const float* __restrict__ ew,
                                                     const float* __restrict__ support,
                                                     float* __restrict__ out) {
    const int tid  = threadIdx.x;
    const int lane = tid & 31;
    const int e    = blockIdx.x * 8 + (tid >> 5);
    const int   src = ei[e];
    const int   dst = ei[NEDGES + e];
    const float w   = ew[e];
    const float4* s4 = (const float4*)support;
    float4 v = s4[(size_t)src * (NHID / 4) + lane];
    float* o = out + (size_t)dst * NHID + lane * 4;
    atomicAdd(o + 0, v.x * w);
    atomicAdd(o + 1, v.y * w);
    atomicAdd(o + 2, v.z * w);
    atomicAdd(o + 3, v.w * w);
}

__global__ __launch_bounds__(256) void finalize(float* __restrict__ out,
                                                const float* __restrict__ b) {
    const int i = blockIdx.x * 256 + threadIdx.x;
    float4*       o4 = (float4*)out;
    const float4* b4 = (const float4*)b;
    float4 v  = o4[i];
    float4 bb = b4[i & 31];
    v.x = fmaxf(v.x + bb.x, 0.f);
    v.y = fmaxf(v.y + bb.y, 0.f);
    v.z = fmaxf(v.z + bb.z, 0.f);
    v.w = fmaxf(v.w + bb.w, 0.f);
    o4[i] = v;
}

extern "C" void kernel_launch(void* const* d_in, const int* in_sizes, int n_in,
                              void* d_out, int out_size, void* d_ws, size_t ws_size,
                              hipStream_t stream) {
    const float* x  = (const float*)d_in[0];
    const int*   ei = (const int*)d_in[1];
    const float* ew = (const float*)d_in[2];
    const float* W  = (const float*)d_in[3];
    const float* b  = (const float*)d_in[4];
    float*       out = (float*)d_out;

    char* ws = (char*)d_ws;

    if (ws_size >= WS_NEEDED) {
        unsigned short*     support = (unsigned short*)(ws + SUP_OFF);
        unsigned short*     Wt      = (unsigned short*)(ws + WT_OFF);
        unsigned int*       rcur    = (unsigned int*)(ws + RC_OFF);
        unsigned long long* ebin    = (unsigned long long*)(ws + EBIN_OFF);

        setup_wt_cur<<<160, 256, 0, stream>>>(W, Wt, rcur);
        gemm_fill<<<GEMM_BLOCKS + PARTB, 256, 0, stream>>>(
            x, Wt, support, ei, ew, rcur, ebin);
        gather_range<<<NR, 512, 0, stream>>>(rcur, ebin, support, b, out);
    } else {
        float* support = (float*)(ws + SUP_OFF);
        gemm_xw<<<NNODES / 64, 256, 0, stream>>>(x, W, support);
        hipMemsetAsync(d_out, 0, (size_t)out_size * sizeof(float), stream);
        scatter_edges<<<NEDGES / 8, 256, 0, stream>>>(ei, ew, support, out);
        finalize<<<out_size / 4 / 256, 256, 0, stream>>>(out, b);
    }
}